// Round 3
// baseline (11979.736 us; speedup 1.0000x reference)
//
#include <hip/hip_runtime.h>
#include <hip/hip_bf16.h>

// LSTM: B=64, S=1024, I=1024, H=1024. Inputs f32: x(B,S,I), W_ih(4H,I), W_hh(4H,H), b_ih(4H), b_hh(4H)
// Output f32: (B,S,H) = all hidden states.
//
// Plan: cast to f16 -> big MFMA GEMM for gx = x@W_ih^T (stored [s][b][4H] f16)
//       -> 1024 per-step kernels: gates = gx + h@W_hh^T + b; elementwise LSTM cell.

#define B64 64
#define SS 1024
#define II 1024
#define HH 1024
#define GG 4096  // 4H

typedef _Float16 f16;
typedef _Float16 f16x8 __attribute__((ext_vector_type(8)));
typedef _Float16 f16x4 __attribute__((ext_vector_type(4)));
typedef float f32x4 __attribute__((ext_vector_type(4)));

__device__ __forceinline__ void gload16(const f16* g, f16* l) {
    // async global->LDS, 16B per lane; LDS dest = wave-uniform base + lane*16
    __builtin_amdgcn_global_load_lds((const __attribute__((address_space(1))) void*)g,
                                     (__attribute__((address_space(3))) void*)l, 16, 0, 0);
}

__device__ __forceinline__ float sigmoidf_(float x) {
    return 1.0f / (1.0f + __expf(-x));
}
__device__ __forceinline__ float tanhf_(float x) {
    // tanh(x) = 1 - 2/(1+e^{2x}); safe at both tails (exp->0 or inf)
    return 1.0f - 2.0f / (1.0f + __expf(2.0f * x));
}

// ---------------- cast f32 -> f16, vectorized x4 ----------------
__global__ void castk(const float* __restrict__ in, f16* __restrict__ out, int n4) {
    int i = blockIdx.x * blockDim.x + threadIdx.x;
    if (i < n4) {
        float4 v = ((const float4*)in)[i];
        f16x4 h = { (f16)v.x, (f16)v.y, (f16)v.z, (f16)v.w };
        ((f16x4*)out)[i] = h;
    }
}

// ---------------- init: h0=0, c0=0, bsum = b_ih + b_hh ----------------
__global__ void initk(f16* __restrict__ h0, float* __restrict__ c,
                      float* __restrict__ bsum,
                      const float* __restrict__ b_ih, const float* __restrict__ b_hh) {
    int i = blockIdx.x * blockDim.x + threadIdx.x;  // 65536 threads
    h0[i] = (f16)0.0f;
    c[i] = 0.0f;
    if (i < GG) bsum[i] = b_ih[i] + b_hh[i];
}

// ---------------- input GEMM: C[s*64+b][n] = sum_k x[b*1024+s][k] * W_ih[n][k] ----------------
// m97 structure: 128x128 tile, BK=32, 256 thr (4 waves, 2x2), global_load_lds, 2-barrier loop.
__global__ __launch_bounds__(256) void gemm_gx(const f16* __restrict__ A,   // x_f16 [65536][1024]
                                               const f16* __restrict__ Bm,  // W_ih_f16 [4096][1024]
                                               f16* __restrict__ C) {       // gx [65536][4096]
    __shared__ f16 sA[128 * 32];
    __shared__ f16 sB[128 * 32];
    const int tid = threadIdx.x;
    const int wave = tid >> 6, l = tid & 63;
    const int m0 = blockIdx.y * 128, n0 = blockIdx.x * 128;
    const int wm = (wave >> 1) * 64, wn = (wave & 1) * 64;

    f32x4 acc[4][4];
#pragma unroll
    for (int i = 0; i < 4; ++i)
#pragma unroll
        for (int j = 0; j < 4; ++j) acc[i][j] = (f32x4){0.f, 0.f, 0.f, 0.f};

    // staging addresses: each thread loads 16B (8 f16); 256 thr cover 64 rows x 32k per pass
    const int srow = wave * 16 + (l >> 2);  // 0..63
    const int scol = (l & 3) * 8;
    const f16* gA = A + (size_t)(m0 + srow) * II + scol;
    const f16* gB = Bm + (size_t)(n0 + srow) * II + scol;
    f16* lA = &sA[(wave * 16) * 32];  // wave-uniform LDS base
    f16* lB = &sB[(wave * 16) * 32];

    const int lrA = wm + (l & 15);
    const int lrB = wn + (l & 15);
    const int lk = (l >> 4) * 8;

    for (int kk = 0; kk < II; kk += 32) {
        __syncthreads();  // previous compute done -> safe to overwrite LDS
        gload16(gA + kk, lA);
        gload16(gA + kk + (size_t)64 * II, lA + 64 * 32);
        gload16(gB + kk, lB);
        gload16(gB + kk + (size_t)64 * II, lB + 64 * 32);
        __syncthreads();  // compiler drains vmcnt before barrier -> tiles ready

        f16x8 af[4], bf[4];
#pragma unroll
        for (int t = 0; t < 4; ++t) {
            af[t] = *(const f16x8*)&sA[(lrA + t * 16) * 32 + lk];
            bf[t] = *(const f16x8*)&sB[(lrB + t * 16) * 32 + lk];
        }
#pragma unroll
        for (int i = 0; i < 4; ++i)
#pragma unroll
            for (int j = 0; j < 4; ++j)
                acc[i][j] = __builtin_amdgcn_mfma_f32_16x16x32_f16(af[i], bf[j], acc[i][j], 0, 0, 0);
    }

    // epilogue: D[m=4*(l>>4)+r][n=l&15]; remap row m=b*1024+s -> out row s*64+b
    const int rl = (l >> 4) * 4;
    const int cl = l & 15;
#pragma unroll
    for (int i = 0; i < 4; ++i)
#pragma unroll
        for (int j = 0; j < 4; ++j)
#pragma unroll
            for (int r = 0; r < 4; ++r) {
                int m = m0 + wm + i * 16 + rl + r;
                int n = n0 + wn + j * 16 + cl;
                int row = (m & 1023) * 64 + (m >> 10);
                C[(size_t)row * GG + n] = (f16)acc[i][j][r];
            }
}

// ---------------- one LSTM step ----------------
// grid: 256 blocks = 4 batch-chunks x 64 col-chunks; 256 threads = 4 waves.
// wave g computes gate-g preacts for [16 batch][16 col] via 32 MFMAs over K=1024.
__global__ __launch_bounds__(256) void lstm_step(const f16* __restrict__ hp,  // [64][1024] f16
                                                 f16* __restrict__ hn,        // [64][1024] f16
                                                 float* __restrict__ c,       // [64][1024] f32
                                                 const f16* __restrict__ gx_s,  // [64][4096] f16 (this step)
                                                 const f16* __restrict__ Whh,   // [4096][1024] f16
                                                 const float* __restrict__ bsum,  // [4096]
                                                 float* __restrict__ ys,          // d_out (B,S,H) f32
                                                 int s) {
    __shared__ float lg[4][16][16];  // [gate][batch][col]
    const int tid = threadIdx.x;
    const int wave = tid >> 6, l = tid & 63;
    const int bc = blockIdx.x >> 6;  // batch chunk (0..3)
    const int gc = blockIdx.x & 63;  // col chunk (0..63)

    const f16* hr = hp + (size_t)(bc * 16 + (l & 15)) * HH + (l >> 4) * 8;
    const f16* wr = Whh + (size_t)(wave * HH + gc * 16 + (l & 15)) * HH + (l >> 4) * 8;

    f32x4 acc = (f32x4){0.f, 0.f, 0.f, 0.f};
#pragma unroll 8
    for (int kk = 0; kk < HH; kk += 32) {
        f16x8 a = *(const f16x8*)(hr + kk);
        f16x8 b = *(const f16x8*)(wr + kk);
        acc = __builtin_amdgcn_mfma_f32_16x16x32_f16(a, b, acc, 0, 0, 0);
    }
#pragma unroll
    for (int r = 0; r < 4; ++r) lg[wave][(l >> 4) * 4 + r][l & 15] = acc[r];
    __syncthreads();

    // epilogue: one thread per (batch, col) of this block's 16x16 tile
    const int bl = tid >> 4, jl = tid & 15;
    const int bg = bc * 16 + bl;
    const int jg = gc * 16 + jl;
    float pre[4];
#pragma unroll
    for (int g = 0; g < 4; ++g)
        pre[g] = lg[g][bl][jl] + (float)gx_s[(size_t)bg * GG + g * HH + jg] + bsum[g * HH + jg];

    float ig = sigmoidf_(pre[0]);
    float fg = sigmoidf_(pre[1]);
    float gg = tanhf_(pre[2]);
    float og = sigmoidf_(pre[3]);

    size_t ci = (size_t)bg * HH + jg;
    float cn = fg * c[ci] + ig * gg;
    c[ci] = cn;
    float hv = og * tanhf_(cn);
    hn[ci] = (f16)hv;
    ys[(size_t)bg * (SS * HH) + (size_t)s * HH + jg] = hv;
}

extern "C" void kernel_launch(void* const* d_in, const int* in_sizes, int n_in,
                              void* d_out, int out_size, void* d_ws, size_t ws_size,
                              hipStream_t stream) {
    const float* x = (const float*)d_in[0];
    const float* W_ih = (const float*)d_in[1];
    const float* W_hh = (const float*)d_in[2];
    const float* b_ih = (const float*)d_in[3];
    const float* b_hh = (const float*)d_in[4];
    float* out = (float*)d_out;

    char* ws = (char*)d_ws;
    const size_t NX = (size_t)B64 * SS * II;  // 67,108,864
    const size_t NW = (size_t)GG * II;        // 4,194,304
    f16* x16 = (f16*)(ws);
    f16* wih16 = (f16*)(ws + 134217728);
    f16* whh16 = (f16*)(ws + 142606336);
    f16* gx16 = (f16*)(ws + 150994944);       // 536,870,912 B
    f16* h0 = (f16*)(ws + 687865856);
    f16* h1 = (f16*)(ws + 687996928);
    float* cst = (float*)(ws + 688128000);
    float* bsum = (float*)(ws + 688390144);

    // 1) casts
    castk<<<(int)(NX / 4 / 256), 256, 0, stream>>>(x, x16, (int)(NX / 4));
    castk<<<(int)(NW / 4 / 256), 256, 0, stream>>>(W_ih, wih16, (int)(NW / 4));
    castk<<<(int)(NW / 4 / 256), 256, 0, stream>>>(W_hh, whh16, (int)(NW / 4));

    // 2) init h0, c, bias sum
    initk<<<256, 256, 0, stream>>>(h0, cst, bsum, b_ih, b_hh);

    // 3) gx GEMM: grid (N/128, M/128) = (32, 512)
    dim3 ggrid(GG / 128, (B64 * SS) / 128);
    gemm_gx<<<ggrid, 256, 0, stream>>>(x16, wih16, gx16);

    // 4) recurrence: 1024 steps, double-buffered h
    for (int s = 0; s < SS; ++s) {
        const f16* hp = (s & 1) ? h1 : h0;
        f16* hn = (s & 1) ? h0 : h1;
        lstm_step<<<256, 256, 0, stream>>>(hp, hn, cst, gx16 + (size_t)s * B64 * GG,
                                           whh16, bsum, out, s);
    }
}